// Round 4
// baseline (229.967 us; speedup 1.0000x reference)
//
#include <hip/hip_runtime.h>

typedef int   int4v   __attribute__((ext_vector_type(4)));
typedef float float4v __attribute__((ext_vector_type(4)));

#define T_TOK 16384
#define HD    1024
#define IE    256
#define EN    8
#define VSZ   100000

// meta[] int indices
#define M_OFF 16   // [9] group offsets
#define M_TS1 25   // [9] gemm tile-start prefix (Mtile=64)

// ws byte offsets (all 16-aligned)
#define XQ_OFF   0ull           // T*1024 int8 (token-ordered)
#define PB1_OFF  21053440ull    // 8*64*512*16 int8 (gate|up packed)
#define PB2_OFF  25247744ull    // 8*16*1024*16 int8 (down packed)
#define PERM_OFF 27344896ull    // T int32
#define XS_OFF   27410688ull    // T float (token-ordered)
#define META_OFF 27542272ull    // 64 int32
#define BC_OFF   27542528ull    // 64*8 int32 per-block histograms
#define BB_OFF   27544576ull    // 64*8 int32 per-block bases

// async global->LDS, 16B per lane; LDS dest = wave-uniform base + lane*16
__device__ __forceinline__ void gload16(const void* g, void* l) {
    __builtin_amdgcn_global_load_lds(
        (const __attribute__((address_space(1))) unsigned int*)g,
        (__attribute__((address_space(3))) unsigned int*)l,
        16, 0, 0);
}

// LDS-only barrier: does NOT drain vmcnt (keeps async stages in flight)
#define LDS_BAR() do { \
    asm volatile("s_waitcnt lgkmcnt(0)" ::: "memory"); \
    __builtin_amdgcn_s_barrier(); \
    __builtin_amdgcn_sched_barrier(0); \
} while (0)

// per-block histogram -> bc[block][e]  (no global atomics)
__global__ void k_hist(const int* __restrict__ ids, const int* __restrict__ t2e,
                       int* __restrict__ bc) {
    __shared__ int h[EN];
    if (threadIdx.x < EN) h[threadIdx.x] = 0;
    __syncthreads();
    int t = blockIdx.x * 256 + threadIdx.x;
    int id = ids[t]; id = min(max(id, 0), VSZ - 1);
    atomicAdd(&h[t2e[id]], 1);
    __syncthreads();
    if (threadIdx.x < EN) bc[blockIdx.x * EN + threadIdx.x] = h[threadIdx.x];
}

// single block, 8 waves (one per expert): prefix over 64 blocks via shuffles
__global__ __launch_bounds__(512) void k_scan(const int* __restrict__ bc,
                                              int* __restrict__ bbase,
                                              int* __restrict__ meta) {
    int e = threadIdx.x >> 6;
    int b = threadIdx.x & 63;
    int c = bc[b * EN + e];
    int inc = c;
    #pragma unroll
    for (int s = 1; s < 64; s <<= 1) {
        int v = __shfl_up(inc, s, 64);
        if (b >= s) inc += v;
    }
    int exc = inc - c;
    __shared__ int tot[EN];
    __shared__ int goff[EN];
    if (b == 63) tot[e] = inc;
    __syncthreads();
    if (threadIdx.x == 0) {
        int off = 0, t1 = 0;
        meta[M_OFF] = 0; meta[M_TS1] = 0;
        #pragma unroll
        for (int i = 0; i < EN; ++i) {
            goff[i] = off;
            int cc = tot[i];
            off += cc; t1 += (cc + 63) >> 6;
            meta[M_OFF + i + 1] = off;
            meta[M_TS1 + i + 1] = t1;
        }
    }
    __syncthreads();
    bbase[b * EN + e] = goff[e] + exc;
}

// LDS cursors seeded from bbase -> zero global atomics
__global__ void k_assign(const int* __restrict__ ids, const int* __restrict__ t2e,
                         const int* __restrict__ bbase, int* __restrict__ perm) {
    __shared__ int cur[EN];
    if (threadIdx.x < EN) cur[threadIdx.x] = bbase[blockIdx.x * EN + threadIdx.x];
    __syncthreads();
    int t = blockIdx.x * 256 + threadIdx.x;
    int id = ids[t]; id = min(max(id, 0), VSZ - 1);
    int e = t2e[id];
    int slot = atomicAdd(&cur[e], 1);
    perm[slot] = t;
}

// ---------------------------------------------------------------------------
// k_pre: token-ordered activation quantization (blocks 0..4095, wave per token)
//        + weight repack into MFMA fragment layout (blocks 4096..5631).
// Fragment layout: elem(k,n) at ((k>>4)*N + n)*16 + (k&15)
// ---------------------------------------------------------------------------
__global__ __launch_bounds__(256) void k_pre(const float* __restrict__ hidden,
                                             const int* __restrict__ gq,
                                             const int* __restrict__ uq,
                                             const int* __restrict__ dq,
                                             signed char* __restrict__ xq,
                                             float* __restrict__ xs,
                                             signed char* __restrict__ pb1,
                                             signed char* __restrict__ pb2) {
    int b = blockIdx.x;
    if (b < 4096) {
        int w = threadIdx.x >> 6, lane = threadIdx.x & 63;
        int token = (b << 2) + w;
        const float* row = hidden + (size_t)token * HD;
        float v[16];
        #pragma unroll
        for (int j = 0; j < 4; ++j) {
            float4v f = *(const float4v*)(row + lane * 16 + j * 4);
            v[j*4+0] = f[0]; v[j*4+1] = f[1]; v[j*4+2] = f[2]; v[j*4+3] = f[3];
        }
        float mx = 0.0f;
        #pragma unroll
        for (int j = 0; j < 16; ++j) mx = fmaxf(mx, fabsf(v[j]));
        #pragma unroll
        for (int s = 1; s < 64; s <<= 1) mx = fmaxf(mx, __shfl_xor(mx, s, 64));
        float sc = fmaxf(mx / 127.0f, 1e-8f);
        if (lane == 0) xs[token] = sc;
        int4v pk;
        #pragma unroll
        for (int j = 0; j < 4; ++j) {
            int bb[4];
            #pragma unroll
            for (int u = 0; u < 4; ++u) {
                float t = rintf(v[j*4+u] / sc);           // round-half-even == jnp.round
                t = fminf(fmaxf(t, -128.0f), 127.0f);
                bb[u] = (int)t;
            }
            pk[j] = (bb[0] & 255) | ((bb[1] & 255) << 8) | ((bb[2] & 255) << 16) | (bb[3] << 24);
        }
        *(int4v*)(xq + (size_t)token * HD + lane * 16) = pk;
    } else {
        int idx = (b - 4096) * 256 + threadIdx.x;   // 0 .. 393215
        if (idx < 262144) {                          // gate|up fragments [8][64][512]
            int n = idx & 511, kc = (idx >> 9) & 63, e = idx >> 15;
            const int* src = (n < 256) ? gq + (((size_t)((e << 10) + (kc << 4)) << 8) + n)
                                       : uq + (((size_t)((e << 10) + (kc << 4)) << 8) + (n - 256));
            int4v pk;
            #pragma unroll
            for (int jj = 0; jj < 4; ++jj) {
                int b0 = src[(size_t)(jj * 4 + 0) << 8], b1 = src[(size_t)(jj * 4 + 1) << 8];
                int b2 = src[(size_t)(jj * 4 + 2) << 8], b3 = src[(size_t)(jj * 4 + 3) << 8];
                pk[jj] = (b0 & 255) | ((b1 & 255) << 8) | ((b2 & 255) << 16) | (b3 << 24);
            }
            *(int4v*)(pb1 + ((size_t)((((e << 6) + kc) << 9) + n) << 4)) = pk;
        } else {                                     // down fragments [8][16][1024]
            int j = idx - 262144;
            int n = j & 1023, kc = (j >> 10) & 15, e = j >> 14;
            const int* src = dq + (((size_t)((e << 8) + (kc << 4)) << 10) + n);
            int4v pk;
            #pragma unroll
            for (int jj = 0; jj < 4; ++jj) {
                int b0 = src[(size_t)(jj * 4 + 0) << 10], b1 = src[(size_t)(jj * 4 + 1) << 10];
                int b2 = src[(size_t)(jj * 4 + 2) << 10], b3 = src[(size_t)(jj * 4 + 3) << 10];
                pk[jj] = (b0 & 255) | ((b1 & 255) << 8) | ((b2 & 255) << 16) | (b3 << 24);
            }
            *(int4v*)(pb2 + ((size_t)((((e << 4) + kc) << 10) + n) << 4)) = pk;
        }
    }
}

// ---------------------------------------------------------------------------
// k_mlp: Mtile=64 fused MLP with a DEPTH-3 counted-vmcnt pipeline (T3+T4).
// 24 stages (16 gate|up + 8 down), unified rotation buf = stage%3.
// Per iter: s_waitcnt vmcnt(N) [exactly one younger stage left in flight] ->
// s_barrier -> sched_barrier(0) -> issue S(t+2) -> compute S(t).
// vmcnt never drains to 0 in the main loops; the inter-GEMM epilogue uses
// lgkm-only barriers so the two in-flight down-weight stages ride through.
// Stage sizes per wave: G1 = 9 gloads, G2 = 8 gloads (vmcnt units are exact;
// all other global accesses hoisted above the pipeline).
// WAR safety: stage t+2 writes buf (t+2)%3 == (t-1)%3, whose readers all
// passed the iteration-t barrier with lgkmcnt(0) enforced.
// LDS: lB[3][32KB] + arena 16KB = 112KB -> 1 block/CU.
// arena: lA bufs @0/4096/8192, pmax@12288, rsc@13312, ptok@13568;
// requantized 64x256 iq tile overlays the whole arena for phase 3.
// ---------------------------------------------------------------------------
__global__ __launch_bounds__(256, 1) void k_mlp(const signed char* __restrict__ xq,
                                                const signed char* __restrict__ pb1,
                                                const signed char* __restrict__ pb2,
                                                const float* __restrict__ xs,
                                                const float* __restrict__ gsc,
                                                const float* __restrict__ usc,
                                                const float* __restrict__ dsc,
                                                const int* __restrict__ meta,
                                                const int* __restrict__ perm,
                                                float* __restrict__ out) {
    int b = (blockIdx.x & 7) * 33 + (blockIdx.x >> 3);   // 264 = 8*33, bijective
    int e = -1, m0 = 0, gend = 0;
    #pragma unroll
    for (int i = 0; i < EN; ++i) {
        int s0 = meta[M_TS1 + i], s1 = meta[M_TS1 + i + 1];
        if (b >= s0 && b < s1) { e = i; m0 = meta[M_OFF + i] + ((b - s0) << 6); gend = meta[M_OFF + i + 1]; }
    }
    if (e < 0) return;   // block-uniform: whole block exits together
    const int w = threadIdx.x >> 6, lane = threadIdx.x & 63;
    const int q = lane >> 4, r = lane & 15;

    __shared__ __align__(16) signed char lB[3][32768];
    __shared__ __align__(16) signed char arena[16384];
    float* pmax = (float*)(arena + 12288);   // [4][64]
    float* rsc  = (float*)(arena + 13312);   // [64]
    int*   ptok = (int*)(arena + 13568);     // [64]

    if (threadIdx.x < 64) ptok[threadIdx.x] = perm[min(m0 + (int)threadIdx.x, T_TOK - 1)];
    __syncthreads();   // pre-pipeline: full drain is fine here

    int tokr[4][4];
    #pragma unroll
    for (int mi = 0; mi < 4; ++mi)
        #pragma unroll
        for (int g = 0; g < 4; ++g)
            tokr[mi][g] = ptok[(mi << 4) + (q << 2) + g];

    const signed char* pbe1 = pb1 + (size_t)e * (64 * 512 * 16);
    const signed char* pbe2 = pb2 + (size_t)e * (16 * 1024 * 16);
    const int arow = (w << 4) + (lane >> 2);          // staging row 0..63
    const int acq  = (lane & 3) ^ ((lane >> 2) & 3);  // swizzled q-slot content
    const signed char* ga_base = xq + (size_t)ptok[arow] * HD + (acq << 4);

    // hoist ALL scalar loads before the pipeline so vmcnt arithmetic is exact
    float gs[4], us[4];
    #pragma unroll
    for (int i = 0; i < 4; ++i) {
        int n = (w << 6) + (i << 4) + r;
        gs[i] = gsc[e * IE + n];
        us[i] = usc[e * IE + n];
    }
    float xsr[4][4];
    #pragma unroll
    for (int mi = 0; mi < 4; ++mi)
        #pragma unroll
        for (int g = 0; g < 4; ++g)
            xsr[mi][g] = xs[tokr[mi][g]];
    float ds16[2][8];
    #pragma unroll
    for (int nh = 0; nh < 2; ++nh)
        #pragma unroll
        for (int i = 0; i < 8; ++i)
            ds16[nh][i] = dsc[e * HD + (nh << 9) + (w << 7) + (i << 4) + r];

    #define G1_STAGE(buf, kt)                                                          \
        {                                                                              \
            int kc0 = (kt) << 2;                                                       \
            _Pragma("unroll")                                                          \
            for (int j = 0; j < 8; ++j) {                                              \
                int n = ((j << 6) + lane) ^ ((w & 1) << 3);                            \
                gload16(pbe1 + (((size_t)(kc0 + w) * 512 + n) << 4),                   \
                        &lB[buf][((w << 3) + j) << 10]);                               \
            }                                                                          \
            gload16(ga_base + ((kt) << 6), arena + ((buf) << 12) + (w << 10));         \
        }

    #define G2_STAGE(buf, st2)                                                         \
        {                                                                              \
            int kc0 = ((st2) & 3) << 2; int nhs = (st2) >> 2;                          \
            _Pragma("unroll")                                                          \
            for (int j = 0; j < 8; ++j) {                                              \
                int n = ((j << 6) + lane) ^ ((w & 1) << 3);                            \
                gload16(pbe2 + (((size_t)(kc0 + w) * 1024 + (nhs << 9) + n) << 4),     \
                        &lB[buf][((w << 3) + j) << 10]);                               \
            }                                                                          \
        }

    int4v zero = {0, 0, 0, 0};
    int4v accg[4][4], accu[4][4];
    #pragma unroll
    for (int mi = 0; mi < 4; ++mi)
        #pragma unroll
        for (int i = 0; i < 4; ++i) { accg[mi][i] = zero; accu[mi][i] = zero; }

    // pipeline prologue: 2 stages in flight (18 loads/wave outstanding)
    G1_STAGE(0, 0);
    G1_STAGE(1, 1);

    // ---------------- phase 1: gate|up GEMM, stages 0..15 ----------------
    for (int kt = 0; kt < 16; ++kt) {
        if (kt < 15) { asm volatile("s_waitcnt vmcnt(9) lgkmcnt(0)" ::: "memory"); }
        else         { asm volatile("s_waitcnt vmcnt(8) lgkmcnt(0)" ::: "memory"); }
        __builtin_amdgcn_s_barrier();
        __builtin_amdgcn_sched_barrier(0);
        int nxt = kt + 2;
        if (nxt < 16)      { G1_STAGE(nxt % 3, nxt); }
        else if (nxt < 18) { G2_STAGE(nxt % 3, nxt - 16); }
        int cur = kt % 3;
        int4v a[4];
        #pragma unroll
        for (int mi = 0; mi < 4; ++mi)
            a[mi] = *(const int4v*)&arena[(cur << 12) + ((((mi << 4) + r) << 6) + ((q ^ (r & 3)) << 4))];
        #pragma unroll
        for (int i = 0; i < 4; ++i) {
            int n = (w << 6) + (i << 4) + r;
            int sg = (q << 9) + (n ^ ((q & 1) << 3));
            int su = (q << 9) + ((n + 256) ^ ((q & 1) << 3));
            int4v bg = *(const int4v*)&lB[cur][sg << 4];
            int4v bu = *(const int4v*)&lB[cur][su << 4];
            #pragma unroll
            for (int mi = 0; mi < 4; ++mi) {
                accg[mi][i] = __builtin_amdgcn_mfma_i32_16x16x64_i8(a[mi], bg, accg[mi][i], 0, 0, 0);
                accu[mi][i] = __builtin_amdgcn_mfma_i32_16x16x64_i8(a[mi], bu, accu[mi][i], 0, 0, 0);
            }
        }
    }
    #undef G1_STAGE

    // ------- epilogue: silu*up, row max, requant (lgkm-only barriers) -------
    float inter[4][4][4];
    float pm[4][4];
    #pragma unroll
    for (int mi = 0; mi < 4; ++mi)
        #pragma unroll
        for (int g = 0; g < 4; ++g) {
            float mx = 0.0f;
            #pragma unroll
            for (int i = 0; i < 4; ++i) {
                float gv = (float)accg[mi][i][g] * xsr[mi][g] * gs[i];
                float uv = (float)accu[mi][i][g] * xsr[mi][g] * us[i];
                float sg = gv / (1.0f + expf(-gv));
                float vv = sg * uv;
                inter[mi][i][g] = vv;
                mx = fmaxf(mx, fabsf(vv));
            }
            #pragma unroll
            for (int s = 1; s < 16; s <<= 1) mx = fmaxf(mx, __shfl_xor(mx, s, 64));
            pm[mi][g] = mx;
        }

    if (r == 0) {
        #pragma unroll
        for (int mi = 0; mi < 4; ++mi)
            #pragma unroll
            for (int g = 0; g < 4; ++g)
                pmax[(w << 6) + (mi << 4) + (q << 2) + g] = pm[mi][g];
    }
    LDS_BAR();   // B1: pmax published; all waves past compute-15 (lA reads done)
    if (threadIdx.x < 64) {
        int row = threadIdx.x;
        float mx = fmaxf(fmaxf(pmax[row], pmax[64 + row]), fmaxf(pmax[128 + row], pmax[192 + row]));
        rsc[row] = fmaxf(mx / 127.0f, 1e-8f);
    }
    LDS_BAR();   // B2: rsc published
    float rscr[4][4];
    #pragma unroll
    for (int mi = 0; mi < 4; ++mi)
        #pragma unroll
        for (int g = 0; g < 4; ++g)
            rscr[mi][g] = rsc[(mi << 4) + (q << 2) + g];
    LDS_BAR();   // B3: all rsc reads done -> safe to overlay arena

    // quantize inter -> swizzled LDS iq tile (overlays whole 16KB arena)
    #pragma unroll
    for (int mi = 0; mi < 4; ++mi)
        #pragma unroll
        for (int g = 0; g < 4; ++g) {
            int row = (mi << 4) + (q << 2) + g;
            float sc = rscr[mi][g];
            #pragma unroll
            for (int i = 0; i < 4; ++i) {
                float t = rintf(inter[mi][i][g] / sc);
                t = fminf(fmaxf(t, -128.0f), 127.0f);
                arena[(row << 8) + ((((w << 2) + i) ^ (row & 3)) << 4) + r] = (signed char)(int)t;
            }
        }
    // iq tile is published by the first phase-3 barrier (includes lgkmcnt(0))

    // ---------------- phase 3: down GEMM, stages 16..23 ----------------
    int4v acc2[4][8];
    for (int st = 0; st < 8; ++st) {     // stage 16+st; st = nh*4 + kt2
        if (st < 7) { asm volatile("s_waitcnt vmcnt(8) lgkmcnt(0)" ::: "memory"); }
        else        { asm volatile("s_waitcnt vmcnt(0) lgkmcnt(0)" ::: "memory"); }
        __builtin_amdgcn_s_barrier();
        __builtin_amdgcn_sched_barrier(0);
        if (st + 2 < 8) { G2_STAGE((18 + st) % 3, st + 2); }
        if ((st & 3) == 0) {
            #pragma unroll
            for (int mi = 0; mi < 4; ++mi)
                #pragma unroll
                for (int i = 0; i < 8; ++i) acc2[mi][i] = zero;
        }
        int cur = (16 + st) % 3;
        int4v a2[4];
        #pragma unroll
        for (int mi = 0; mi < 4; ++mi) {
            int row2 = (mi << 4) + r;
            a2[mi] = *(const int4v*)&arena[(row2 << 8) + (((((st & 3) << 2) + q) ^ (r & 3)) << 4)];
        }
        #pragma unroll
        for (int i = 0; i < 8; ++i) {
            int n = (w << 7) + (i << 4) + r;
            int sb = (q << 9) + (n ^ ((q & 1) << 3));
            int4v bb = *(const int4v*)&lB[cur][sb << 4];
            #pragma unroll
            for (int mi = 0; mi < 4; ++mi)
                acc2[mi][i] = __builtin_amdgcn_mfma_i32_16x16x64_i8(a2[mi], bb, acc2[mi][i], 0, 0, 0);
        }
        if ((st & 3) == 3) {
            int nhs = st >> 2;
            #pragma unroll
            for (int mi = 0; mi < 4; ++mi)
                #pragma unroll
                for (int g = 0; g < 4; ++g) {
                    int slot = m0 + (mi << 4) + (q << 2) + g;
                    if (slot < gend) {
                        size_t ob = (size_t)tokr[mi][g] * HD + (nhs << 9) + (w << 7) + r;
                        #pragma unroll
                        for (int i = 0; i < 8; ++i)
                            out[ob + (i << 4)] = (float)acc2[mi][i][g] * rscr[mi][g] * ds16[nhs][i];
                    }
                }
        }
    }
    #undef G2_STAGE
}

extern "C" void kernel_launch(void* const* d_in, const int* in_sizes, int n_in,
                              void* d_out, int out_size, void* d_ws, size_t ws_size,
                              hipStream_t stream) {
    const float* hidden = (const float*)d_in[0];
    const int*   ids    = (const int*)d_in[1];
    const int*   gq     = (const int*)d_in[2];
    const float* gsc    = (const float*)d_in[3];
    const int*   uq     = (const int*)d_in[4];
    const float* usc    = (const float*)d_in[5];
    const int*   dq     = (const int*)d_in[6];
    const float* dsc    = (const float*)d_in[7];
    const int*   t2e    = (const int*)d_in[8];
    float* out = (float*)d_out;

    char* ws = (char*)d_ws;
    signed char* xq  = (signed char*)(ws + XQ_OFF);
    signed char* pb1 = (signed char*)(ws + PB1_OFF);
    signed char* pb2 = (signed char*)(ws + PB2_OFF);
    int*   perm = (int*)(ws + PERM_OFF);
    float* xs   = (float*)(ws + XS_OFF);
    int*   meta = (int*)(ws + META_OFF);
    int*   bc   = (int*)(ws + BC_OFF);
    int*   bbase= (int*)(ws + BB_OFF);

    k_hist<<<64, 256, 0, stream>>>(ids, t2e, bc);
    k_scan<<<1, 512, 0, stream>>>(bc, bbase, meta);
    k_assign<<<64, 256, 0, stream>>>(ids, t2e, bbase, perm);
    k_pre<<<5632, 256, 0, stream>>>(hidden, gq, uq, dq, xq, xs, pb1, pb2);
    k_mlp<<<264, 256, 0, stream>>>(xq, pb1, pb2, xs, gsc, usc, dsc, meta, perm, out);
}